// Round 1
// baseline (75.637 us; speedup 1.0000x reference)
//
#include <hip/hip_runtime.h>

#define LOG2E 1.4426950408889634f

constexpr int D      = 2048;
constexpr int NB     = 16;       // train buffer rows
constexpr int TPB    = 512;      // threads per block (8 waves)
constexpr int F4     = D / 4;    // 512 float4 per row -> 1 per thread
constexpr int RPB    = 8;        // rows per block
constexpr int NROWS  = 16384;    // B*T

__device__ __forceinline__ float gelu_tanh_f(float x) {
    const float C = 0.7978845608028654f;   // sqrt(2/pi)
    const float K = 0.044715f;
    float x2 = x * x;
    float p  = __builtin_fmaf(K, x2, 1.0f);
    float z  = C * x * p;                   // c*(x + K x^3)
    // tanh(z) = 1 - 2/(exp(2z)+1); exp via exp2. Overflow -> inf -> tanh=1 (correct).
    float e  = __builtin_amdgcn_exp2f(z * (2.0f * LOG2E));
    float th = 1.0f - 2.0f * __builtin_amdgcn_rcpf(e + 1.0f);
    float hx = 0.5f * x;
    return __builtin_fmaf(hx, th, hx);      // 0.5x(1+tanh)
}

__global__ __launch_bounds__(TPB) void gelu_gate_kernel(
    const float* __restrict__ x,
    const float* __restrict__ buf,
    const int* __restrict__ mask_i,
    const unsigned char* __restrict__ mask_b,
    const float* __restrict__ p_log_tau,
    const float* __restrict__ p_log_blend,
    float* __restrict__ out)
{
    __shared__ float part[NB][TPB];     // 32 KiB: per-thread dot partials
    __shared__ float s2part[TPB / 64];  // per-wave ||y||^2 partials
    __shared__ float stage2[NB][33];    // padded
    __shared__ float gate_sh;

    const int t    = threadIdx.x;
    const int lane = t & 63;
    const int wave = t >> 6;

    // Per-block uniform scalars
    const float tau   = __builtin_amdgcn_exp2f(p_log_tau[0] * LOG2E);
    const float lbt   = p_log_blend[0];
    const float alpha = __builtin_amdgcn_rcpf(1.0f + __builtin_amdgcn_exp2f(-lbt * LOG2E));

    // Mask: dtype layout of bool is ambiguous (u8 vs i32) -> accept either.
    unsigned mbits = 0;
#pragma unroll
    for (int k = 0; k < NB; ++k) {
        bool mk = (mask_i[k] != 0) || (mask_b[k] != 0);
        mbits |= (mk ? 1u : 0u) << k;
    }

    // Stage the 16x2048 train buffer slice for this thread into VGPRs (64 regs).
    const float4* buf4 = reinterpret_cast<const float4*>(buf);
    float4 bv[NB];
#pragma unroll
    for (int k = 0; k < NB; ++k) bv[k] = buf4[k * F4 + t];

    const float4* x4   = reinterpret_cast<const float4*>(x);
    float4*       out4 = reinterpret_cast<float4*>(out);

    const int row0 = blockIdx.x * RPB;
    float4 xv = x4[(size_t)row0 * F4 + t];

    for (int r = 0; r < RPB; ++r) {
        const int row = row0 + r;
        float4 xn;
        if (r + 1 < RPB) xn = x4[(size_t)(row + 1) * F4 + t];  // prefetch next row

        float4 y;
        y.x = gelu_tanh_f(xv.x);
        y.y = gelu_tanh_f(xv.y);
        y.z = gelu_tanh_f(xv.z);
        y.w = gelu_tanh_f(xv.w);

        float s2 = y.x * y.x;
        s2 = __builtin_fmaf(y.y, y.y, s2);
        s2 = __builtin_fmaf(y.z, y.z, s2);
        s2 = __builtin_fmaf(y.w, y.w, s2);

        // 16 per-thread dot partials -> LDS transpose layout
#pragma unroll
        for (int k = 0; k < NB; ++k) {
            float dk = y.x * bv[k].x;
            dk = __builtin_fmaf(y.y, bv[k].y, dk);
            dk = __builtin_fmaf(y.z, bv[k].z, dk);
            dk = __builtin_fmaf(y.w, bv[k].w, dk);
            part[k][t] = dk;
        }

        // ||y||^2: cheap wave butterfly + cross-wave via LDS
#pragma unroll
        for (int off = 1; off < 64; off <<= 1)
            s2 += __shfl_xor(s2, off, 64);
        if (lane == 0) s2part[wave] = s2;

        __syncthreads();

        float s2t = 0.f;
#pragma unroll
        for (int w = 0; w < TPB / 64; ++w) s2t += s2part[w];
        const float nrm = __builtin_sqrtf(s2t);
        const float inv = __builtin_amdgcn_rcpf(fmaxf(nrm, 1e-12f));

        // stage2: 512 partials per dot -> 32 partials per dot
        {
            const int j = t >> 5;   // 0..15  (which dot)
            const int s = t & 31;
            float acc = 0.f;
#pragma unroll
            for (int i = 0; i < 16; ++i) acc += part[j][s + 32 * i];
            stage2[j][s] = acc;
        }
        __syncthreads();

        // stage3: lanes 0..15 of wave 0 finish dots, masked max, gate
        if (t < NB) {
            float d = 0.f;
#pragma unroll
            for (int i = 0; i < 32; ++i) d += stage2[t][i];
            float sim = d * inv;
            sim = ((mbits >> t) & 1u) ? sim : -1.0f;
#pragma unroll
            for (int off = 8; off >= 1; off >>= 1)
                sim = fmaxf(sim, __shfl_xor(sim, off, 64));
            if (t == 0) {
                const float g = __builtin_amdgcn_exp2f(-tau * sim * LOG2E);
                gate_sh = __builtin_fmaf(alpha, g, 1.0f - alpha);
            }
        }
        __syncthreads();

        const float gate = gate_sh;
        float4 o;
        o.x = y.x * gate;
        o.y = y.y * gate;
        o.z = y.z * gate;
        o.w = y.w * gate;
        out4[(size_t)row * F4 + t] = o;

        xv = xn;
    }
}

extern "C" void kernel_launch(void* const* d_in, const int* in_sizes, int n_in,
                              void* d_out, int out_size, void* d_ws, size_t ws_size,
                              hipStream_t stream) {
    const float*         x      = (const float*)d_in[0];
    const float*         buf    = (const float*)d_in[1];
    const int*           mask_i = (const int*)d_in[2];
    const unsigned char* mask_b = (const unsigned char*)d_in[2];
    const float*         lt     = (const float*)d_in[3];
    const float*         lb     = (const float*)d_in[4];
    float*               out    = (float*)d_out;

    gelu_gate_kernel<<<NROWS / RPB, TPB, 0, stream>>>(x, buf, mask_i, mask_b, lt, lb, out);
}